// Round 6
// baseline (1893.937 us; speedup 1.0000x reference)
//
#include <hip/hip_runtime.h>

// Bidirectional masked LSTM encoder, MI355X gfx950.
// V=50000 E=300 H=256 T=512 B=64.
// Round 6: same structure as round 5 (16 blocks = 8 chains x 2 col-halves,
// 512 thr, sibling h-exchange via system-scope atomics), but U fragments are
// PINNED into VGPRs with empty inline-asm so the compiler cannot re-load
// them inside the loop (round 5: VGPR=116 -> U re-streamed from L2 every
// step, ~2 us/step). launch_bounds(512,1) lifts the VGPR cap.

#define T_ 512
#define B_ 64
#define E_ 300
#define FOURH 1024

typedef float floatx4 __attribute__((ext_vector_type(4)));
typedef __bf16 bf16x8 __attribute__((ext_vector_type(8)));

// ws layout (bytes):
//   xpf  (bf16 frag-packed xproj): 2*2048*64*64*4*2B = 134217728  @ 0
//   xpack(bf16): 2048*10*64*8*2 =  20971520   @ 134217728
//   wp   (bf16): 2*64*10*64*8*2 =   1310720   @ 155189248
//   up   (bf16): 2*64*8*64*8*2  =   1048576   @ 156499968
//   hx   : 8 pairs * 2 halves * 2 parity * 4096 B = 131072 @ 157548544
//   flags: 16 ints (padded 4096) @ 157679616
#define WS_XPACK_OFF 134217728ull
#define WS_WP_OFF    155189248ull
#define WS_UP_OFF    156499968ull
#define WS_HX_OFF    157548544ull
#define WS_FLAG_OFF  157679616ull
#define WS_NEEDED    157683712ull

#define OUT_H_OFF    16777216ull
#define OUT_C_OFF    16809984ull
#define OUT_M_OFF    16842752ull

__device__ __forceinline__ unsigned short f2bf(float f) {
    unsigned int u = __builtin_bit_cast(unsigned int, f);
    u += 0x7fffu + ((u >> 16) & 1u);
    return (unsigned short)(u >> 16);
}
__device__ __forceinline__ float bf2f(unsigned short b) {
    unsigned int u = ((unsigned int)b) << 16;
    return __builtin_bit_cast(float, u);
}

__device__ __forceinline__ float sigf(float x) { return 1.f / (1.f + __expf(-x)); }

__device__ __forceinline__ float tanh_fast(float x) {
    float t = __expf(-2.f * fabsf(x));      // in (0,1], no overflow
    float r = (1.f - t) / (1.f + t);
    return x >= 0.f ? r : -r;
}

// ---------------- pack embedded x into A-fragment order --------------------
__global__ void pack_x_kernel(const int* __restrict__ seq, const float* __restrict__ emb,
                              unsigned short* __restrict__ xpack) {
    const int mtile = blockIdx.x;   // 0..2047
    const int l = threadIdx.x;      // 0..63
    const int row = mtile * 16 + (l & 15);
    const int t = row >> 6, b = row & 63;
    const int token = seq[b * T_ + t];
    const float* src = emb + (size_t)token * E_;
    const int kb = (l >> 4) * 8;
#pragma unroll
    for (int ks = 0; ks < 10; ++ks) {
        const int k0 = ks * 32 + kb;
        unsigned int w[4];
#pragma unroll
        for (int h = 0; h < 4; ++h) {
            int ka = k0 + 2 * h, kbb = ka + 1;
            float fa = (ka < E_) ? src[ka] : 0.f;
            float fb = (kbb < E_) ? src[kbb] : 0.f;
            w[h] = (unsigned int)f2bf(fa) | ((unsigned int)f2bf(fb) << 16);
        }
        uint4* dst = reinterpret_cast<uint4*>(xpack + ((size_t)(mtile * 10 + ks) * 64 + l) * 8);
        *dst = make_uint4(w[0], w[1], w[2], w[3]);
    }
}

// ------------- pack a [Ksrc x 1024] f32 matrix into B-fragment order -------
__global__ void pack_mat_kernel(const float* __restrict__ src, unsigned short* __restrict__ dst,
                                int Ksrc, int nks) {
    const int ks = blockIdx.x;      // 0..nks-1
    const int ntile = blockIdx.y;   // 0..63
    const int l = threadIdx.x;
    const int n = ntile * 16 + (l & 15);
    const int k0 = ks * 32 + (l >> 4) * 8;
    unsigned int w[4];
#pragma unroll
    for (int h = 0; h < 4; ++h) {
        int ka = k0 + 2 * h, kb2 = ka + 1;
        float fa = (ka < Ksrc) ? src[(size_t)ka * FOURH + n] : 0.f;
        float fb = (kb2 < Ksrc) ? src[(size_t)kb2 * FOURH + n] : 0.f;
        w[h] = (unsigned int)f2bf(fa) | ((unsigned int)f2bf(fb) << 16);
    }
    uint4* d = reinterpret_cast<uint4*>(dst + ((size_t)(ntile * nks + ks) * 64 + l) * 8);
    *d = make_uint4(w[0], w[1], w[2], w[3]);
}

// ---------------- xproj = xpack @ Wpack + bias  (LDS-free MFMA GEMM) -------
__global__ __launch_bounds__(256) void gemm_xproj_kernel(
    const unsigned short* __restrict__ xpack, const unsigned short* __restrict__ wp,
    const float* __restrict__ b_fw, const float* __restrict__ b_bw,
    unsigned short* __restrict__ xpf) {
    const int bid = blockIdx.x;
    const int dir = bid >> 11;          // 2048 blocks per dir
    const int rem = bid & 2047;
    const int mb = rem >> 3;            // 0..255
    const int nb = rem & 7;             // 0..7
    const int w = threadIdx.x >> 6;
    const int l = threadIdx.x & 63;
    const int wm = w >> 1, wn = w & 1;
    const unsigned short* wpd = wp + (size_t)dir * (64 * 10 * 64 * 8);
    const float* bias = dir ? b_bw : b_fw;

    floatx4 acc[4][4];
#pragma unroll
    for (int i = 0; i < 4; ++i)
#pragma unroll
        for (int j = 0; j < 4; ++j) acc[i][j] = floatx4{0.f, 0.f, 0.f, 0.f};

#pragma unroll
    for (int ks = 0; ks < 10; ++ks) {
        bf16x8 a[4], bb[4];
#pragma unroll
        for (int mi = 0; mi < 4; ++mi) {
            int mt = mb * 8 + wm * 4 + mi;
            a[mi] = *reinterpret_cast<const bf16x8*>(xpack + ((size_t)(mt * 10 + ks) * 64 + l) * 8);
        }
#pragma unroll
        for (int ni = 0; ni < 4; ++ni) {
            int nt = nb * 8 + wn * 4 + ni;
            bb[ni] = *reinterpret_cast<const bf16x8*>(wpd + ((size_t)(nt * 10 + ks) * 64 + l) * 8);
        }
#pragma unroll
        for (int mi = 0; mi < 4; ++mi)
#pragma unroll
            for (int ni = 0; ni < 4; ++ni)
                acc[mi][ni] = __builtin_amdgcn_mfma_f32_16x16x32_bf16(a[mi], bb[ni], acc[mi][ni], 0, 0, 0);
    }

    unsigned short* xpd = xpf + (size_t)dir * 33554432ull;
#pragma unroll
    for (int mi = 0; mi < 4; ++mi) {
        int mt = mb * 8 + wm * 4 + mi;
#pragma unroll
        for (int ni = 0; ni < 4; ++ni) {
            int nt = nb * 8 + wn * 4 + ni;
            float bv = bias[nt * 16 + (l & 15)];
            unsigned int w0 = (unsigned int)f2bf(acc[mi][ni][0] + bv) |
                              ((unsigned int)f2bf(acc[mi][ni][1] + bv) << 16);
            unsigned int w1 = (unsigned int)f2bf(acc[mi][ni][2] + bv) |
                              ((unsigned int)f2bf(acc[mi][ni][3] + bv) << 16);
            *reinterpret_cast<uint2*>(xpd + (((size_t)mt * 64 + nt) * 64 + l) * 4) = make_uint2(w0, w1);
        }
    }
}

// ---------------- recurrent LSTM: 16 blocks = 8 chains x 2 col-halves ------
// Block (pairIdx = bg*2+dir, half). 512 thr = 8 waves; wave w owns h-coltile
// hct = half*8+w for all 4 gates -> U frags Bf[4][8] = 128 VGPR, PINNED.
// Per step: 4 KB h-half exchanged with sibling via system-scope atomics.
__global__ __launch_bounds__(512, 1) void lstm_rec_kernel(
    const int* __restrict__ seq, const unsigned short* __restrict__ xpf,
    const unsigned short* __restrict__ up, unsigned long long* __restrict__ hx,
    int* __restrict__ flags, float* __restrict__ out) {
    const int bid = blockIdx.x;     // 0..15 ; sibling at bid^8 (same XCD mod-8)
    const int half = bid >> 3;
    const int pairIdx = bid & 7;
    const int bg = pairIdx >> 1;
    const int dir = pairIdx & 1;
    const int sib = 1 - half;
    const int tid = threadIdx.x;
    const int w = tid >> 6;         // 0..7
    const int l = tid & 63;
    const int hct = half * 8 + w;   // h-coltile 0..15
    const unsigned short* xpd = xpf + (size_t)dir * 33554432ull;
    const unsigned short* upd = up + (size_t)dir * 262144;

    __shared__ __align__(16) unsigned short hbuf[2][16 * 256];
    for (int i = tid; i < 16 * 256; i += 512) hbuf[0][i] = 0;

    // U B-fragments, register-resident (128 VGPR). The empty inline-asm makes
    // each fragment an opaque register def: the compiler cannot sink/remat
    // the load into the loop (round-5 failure mode: barrier memory clobbers
    // made it re-load U from L2 every step).
    floatx4 Bf[4][8];
#pragma unroll
    for (int g = 0; g < 4; ++g) {
        const unsigned short* ub = upd + (size_t)(g * 16 + hct) * 4096 + (size_t)l * 8;
#pragma unroll
        for (int ks = 0; ks < 8; ++ks) {
            Bf[g][ks] = *reinterpret_cast<const floatx4*>(ub + (size_t)ks * 512);
            asm volatile("" : "+v"(Bf[g][ks]));
        }
    }

    const int rrb = (l >> 4) * 4;       // cell rows rrb..rrb+3 (batch-local)
    const int hc = hct * 16 + (l & 15); // h column 0..255
    const int arow = l & 15;
    const int akb = (l >> 4) * 8;
    const int axor = (arow & 7) << 3;

    // exchange geometry (per thread: one u64 = 4 ushorts of one row)
    const int rowp = tid >> 5;              // 0..15
    const int c4 = (tid & 31) * 4;          // 0..124
    const int swzp = (rowp & 7) << 3;
    const int myslot  = (pairIdx * 2 + half) * 2;   // + parity
    const int sibslot = (pairIdx * 2 + sib) * 2;
    int* myflag  = &flags[pairIdx * 2 + half];
    int* sibflag = &flags[pairIdx * 2 + sib];

    float h_s[4], c_s[4];
#pragma unroll
    for (int e = 0; e < 4; ++e) { h_s[e] = 0.f; c_s[e] = 0.f; }

    // prefetch xq + tokens for step 0
    uint2 xq_c[4], xq_n[4];
    int tok_c[4], tok_n[4];
    {
        int t0 = dir ? 511 : 0;
        size_t mt0 = (size_t)t0 * 4 + bg;
#pragma unroll
        for (int g = 0; g < 4; ++g)
            xq_c[g] = *reinterpret_cast<const uint2*>(
                xpd + ((mt0 * 64 + (g * 16 + hct)) * 64 + l) * 4);
#pragma unroll
        for (int e = 0; e < 4; ++e) tok_c[e] = seq[(bg * 16 + rrb + e) * T_ + t0];
    }
    __syncthreads();

    int p = 0;
    for (int s = 0; s < 512; ++s) {
        const int t = dir ? (511 - s) : s;

        // A-fragments (full h of previous step) from swizzled LDS
        bf16x8 a[8];
#pragma unroll
        for (int ks = 0; ks < 8; ++ks)
            a[ks] = *reinterpret_cast<const bf16x8*>(&hbuf[p][arow * 256 + ((ks * 32 + akb) ^ axor)]);

        floatx4 acc[4];
#pragma unroll
        for (int g = 0; g < 4; ++g) {
            floatx4 v;
            v[0] = bf2f((unsigned short)(xq_c[g].x & 0xffff));
            v[1] = bf2f((unsigned short)(xq_c[g].x >> 16));
            v[2] = bf2f((unsigned short)(xq_c[g].y & 0xffff));
            v[3] = bf2f((unsigned short)(xq_c[g].y >> 16));
            acc[g] = v;
        }
#pragma unroll
        for (int ks = 0; ks < 8; ++ks)
#pragma unroll
            for (int g = 0; g < 4; ++g)
                acc[g] = __builtin_amdgcn_mfma_f32_16x16x32_bf16(
                    a[ks], __builtin_bit_cast(bf16x8, Bf[g][ks]), acc[g], 0, 0, 0);

        // prefetch next step's xq/tok (overlaps with exchange wait)
        if (s + 1 < 512) {
            int tn = dir ? (511 - (s + 1)) : (s + 1);
            size_t mtn = (size_t)tn * 4 + bg;
#pragma unroll
            for (int g = 0; g < 4; ++g)
                xq_n[g] = *reinterpret_cast<const uint2*>(
                    xpd + ((mtn * 64 + (g * 16 + hct)) * 64 + l) * 4);
#pragma unroll
            for (int e = 0; e < 4; ++e) tok_n[e] = seq[(bg * 16 + rrb + e) * T_ + tn];
        }

        // gates + masked state update + out/hbuf writes (own 16 cols)
#pragma unroll
        for (int e = 0; e < 4; ++e) {
            float ig = sigf(acc[0][e]);
            float fg = sigf(acc[1][e]);
            float gg = tanh_fast(acc[2][e]);
            float og = sigf(acc[3][e]);
            float cn = fg * c_s[e] + ig * gg;
            float hn = og * tanh_fast(cn);
            if (tok_c[e] != 0) { c_s[e] = cn; h_s[e] = hn; }
            int r = rrb + e;
            out[((size_t)((bg * 16 + r) * T_ + t)) * 512 + (size_t)dir * 256 + hc] = h_s[e];
            hbuf[p ^ 1][r * 256 + (hc ^ ((r & 7) << 3))] = f2bf(h_s[e]);
        }

        if (s + 1 < 512) {
            const int parity = (s + 1) & 1;
            __syncthreads();    // own-half hbuf[p^1] complete

            // publish own 4 KB half (linear row-major) via system-scope stores
            {
                unsigned long long v = *reinterpret_cast<const unsigned long long*>(
                    &hbuf[p ^ 1][rowp * 256 + ((half * 128 + c4) ^ swzp)]);
                __hip_atomic_store(&hx[(size_t)(myslot + parity) * 512 + tid], v,
                                   __ATOMIC_RELAXED, __HIP_MEMORY_SCOPE_SYSTEM);
            }
            asm volatile("s_waitcnt vmcnt(0)" ::: "memory");
            __syncthreads();    // all publish stores complete
            if (tid == 0)
                __hip_atomic_store(myflag, s + 1, __ATOMIC_RELAXED, __HIP_MEMORY_SCOPE_SYSTEM);

            // poll sibling flag (bounded), then gather its 4 KB half
            {
                int fl, guard = 0;
                do {
                    fl = __hip_atomic_load(sibflag, __ATOMIC_RELAXED, __HIP_MEMORY_SCOPE_SYSTEM);
                } while (fl < s + 1 && ++guard < 16384);
            }
            asm volatile("" ::: "memory");
            {
                unsigned long long v = __hip_atomic_load(
                    &hx[(size_t)(sibslot + parity) * 512 + tid],
                    __ATOMIC_RELAXED, __HIP_MEMORY_SCOPE_SYSTEM);
                *reinterpret_cast<unsigned long long*>(
                    &hbuf[p ^ 1][rowp * 256 + ((sib * 128 + c4) ^ swzp)]) = v;
            }
            __syncthreads();    // sibling half landed in LDS
        }

        p ^= 1;
#pragma unroll
        for (int g = 0; g < 4; ++g) xq_c[g] = xq_n[g];
#pragma unroll
        for (int e = 0; e < 4; ++e) tok_c[e] = tok_n[e];
    }

    // final carried states
#pragma unroll
    for (int e = 0; e < 4; ++e) {
        int b = bg * 16 + rrb + e;
        out[OUT_H_OFF + (size_t)b * 512 + (size_t)dir * 256 + hc] = h_s[e];
        out[OUT_C_OFF + (size_t)b * 512 + (size_t)dir * 256 + hc] = c_s[e];
    }
}

// ---------------- mask output ----------------------------------------------
__global__ void mask_kernel(const int* __restrict__ seq, float* __restrict__ out) {
    int i = blockIdx.x * 256 + threadIdx.x;
    if (i < B_ * T_) out[OUT_M_OFF + i] = (seq[i] != 0) ? 1.0f : 0.0f;
}

extern "C" void kernel_launch(void* const* d_in, const int* in_sizes, int n_in,
                              void* d_out, int out_size, void* d_ws, size_t ws_size,
                              hipStream_t stream) {
    const int* seq = (const int*)d_in[0];
    // d_in[1]=state_h0, d_in[2]=state_c0: unused by the reference (zero init)
    const float* emb  = (const float*)d_in[3];
    const float* W_fw = (const float*)d_in[4];
    const float* U_fw = (const float*)d_in[5];
    const float* b_fw = (const float*)d_in[6];
    const float* W_bw = (const float*)d_in[7];
    const float* U_bw = (const float*)d_in[8];
    const float* b_bw = (const float*)d_in[9];
    float* out = (float*)d_out;

    // Always produce the mask (writes only to d_out).
    hipLaunchKernelGGL(mask_kernel, dim3(128), dim3(256), 0, stream, seq, out);

    if (ws_size < WS_NEEDED) return;    // diagnostic bail-out

    char* ws = (char*)d_ws;
    unsigned short* xpf   = (unsigned short*)ws;
    unsigned short* xpack = (unsigned short*)(ws + WS_XPACK_OFF);
    unsigned short* wp    = (unsigned short*)(ws + WS_WP_OFF);
    unsigned short* up    = (unsigned short*)(ws + WS_UP_OFF);
    unsigned long long* hx = (unsigned long long*)(ws + WS_HX_OFF);
    int* flags            = (int*)(ws + WS_FLAG_OFF);

    // reset sync flags every launch (graph-replay safe)
    hipMemsetAsync((void*)(ws + WS_FLAG_OFF), 0, 4096, stream);

    hipLaunchKernelGGL(pack_x_kernel, dim3(2048), dim3(64), 0, stream, seq, emb, xpack);
    hipLaunchKernelGGL(pack_mat_kernel, dim3(10, 64), dim3(64), 0, stream, W_fw, wp,          300, 10);
    hipLaunchKernelGGL(pack_mat_kernel, dim3(10, 64), dim3(64), 0, stream, W_bw, wp + 327680, 300, 10);
    hipLaunchKernelGGL(pack_mat_kernel, dim3(8, 64),  dim3(64), 0, stream, U_fw, up,          256, 8);
    hipLaunchKernelGGL(pack_mat_kernel, dim3(8, 64),  dim3(64), 0, stream, U_bw, up + 262144, 256, 8);
    hipLaunchKernelGGL(gemm_xproj_kernel, dim3(4096), dim3(256), 0, stream, xpack, wp, b_fw, b_bw, xpf);
    hipLaunchKernelGGL(lstm_rec_kernel, dim3(16), dim3(512), 0, stream, seq, xpf, up, hx, flags, out);
}